// Round 1
// baseline (280.835 us; speedup 1.0000x reference)
//
#include <hip/hip_runtime.h>

typedef unsigned short u16;
typedef __bf16 bf16x8 __attribute__((ext_vector_type(8)));
typedef float f32x4 __attribute__((ext_vector_type(4)));

#define B_ 16384

__device__ __forceinline__ u16 f2b(float f){
  unsigned u = __builtin_bit_cast(unsigned, f);
  u = (u + 0x7FFFu + ((u >> 16) & 1u)) >> 16;   // RNE
  return (u16)u;
}
__device__ __forceinline__ float b2f(u16 v){
  return __builtin_bit_cast(float, ((unsigned)v) << 16);
}

// ---------------- GEMM core ----------------
// C[128,128] tile at (m0,n0) = A[m0..+128, 0..K) * Wt[n0..+128, 0..K)^T
// A row-major [M][K] bf16, Wt row-major [N][K] bf16 (i.e. B transposed).
// 256 threads = 4 waves in 2x2, each wave 64x64 = 4x4 MFMA 16x16x32 frags.
// LDS tiles [128][64] bf16, XOR-swizzled 16B slots (slot ^= row&7).
__device__ __forceinline__ void gemm_core(const u16* __restrict__ A,
                                          const u16* __restrict__ Wt,
                                          int K, int m0, int n0,
                                          u16* sA, u16* sB,
                                          f32x4 acc[4][4])
{
  const int tid  = threadIdx.x;
  const int lane = tid & 63;
  const int wm   = ((tid >> 7) & 1) * 64;
  const int wn   = ((tid >> 6) & 1) * 64;

  f32x4 zero = {0.f, 0.f, 0.f, 0.f};
  #pragma unroll
  for (int mi = 0; mi < 4; ++mi)
    #pragma unroll
    for (int ni = 0; ni < 4; ++ni)
      acc[mi][ni] = zero;

  const int nsteps = K >> 6;
  for (int ks = 0; ks < nsteps; ++ks) {
    #pragma unroll
    for (int i = 0; i < 4; ++i) {
      int chunk = i * 256 + tid;            // 0..1023 : 128 rows x 8 slots
      int row = chunk >> 3;
      int slot = chunk & 7;
      int sOff = row * 64 + ((slot ^ (row & 7)) << 3);   // ushort offset
      *(uint4*)(sA + sOff) = *(const uint4*)(A  + (size_t)(m0 + row) * K + ks * 64 + slot * 8);
      *(uint4*)(sB + sOff) = *(const uint4*)(Wt + (size_t)(n0 + row) * K + ks * 64 + slot * 8);
    }
    __syncthreads();
    #pragma unroll
    for (int kk = 0; kk < 2; ++kk) {
      bf16x8 av[4], bv[4];
      #pragma unroll
      for (int mi = 0; mi < 4; ++mi) {
        int r = wm + mi * 16 + (lane & 15);
        int slot = kk * 4 + (lane >> 4);
        av[mi] = *(const bf16x8*)(sA + r * 64 + ((slot ^ (r & 7)) << 3));
      }
      #pragma unroll
      for (int ni = 0; ni < 4; ++ni) {
        int r = wn + ni * 16 + (lane & 15);
        int slot = kk * 4 + (lane >> 4);
        bv[ni] = *(const bf16x8*)(sB + r * 64 + ((slot ^ (r & 7)) << 3));
      }
      #pragma unroll
      for (int mi = 0; mi < 4; ++mi)
        #pragma unroll
        for (int ni = 0; ni < 4; ++ni)
          acc[mi][ni] = __builtin_amdgcn_mfma_f32_16x16x32_bf16(av[mi], bv[ni], acc[mi][ni], 0, 0, 0);
    }
    __syncthreads();
  }
}

// ---------------- stage kernels ----------------

// GEMM0: xb[16384,512] x Wt0[2688,512]^T. cols: 0..2047 task experts (t*2+e)*256+o,
// 2048..2559 shared experts, 2560..2575 task-gate logits, 2576..2585 shared-gate logits.
__global__ __launch_bounds__(256) void k_gemm0(const u16* __restrict__ xb,
    const u16* __restrict__ Wt0, const float* __restrict__ bias0,
    u16* __restrict__ E0, float* __restrict__ G0L)
{
  __shared__ __align__(16) u16 sm[2 * 128 * 64];
  f32x4 acc[4][4];
  const int m0 = blockIdx.x * 128, n0 = blockIdx.y * 128;
  gemm_core(xb, Wt0, 512, m0, n0, sm, sm + 8192, acc);
  const int lane = threadIdx.x & 63;
  const int wm = ((threadIdx.x >> 7) & 1) * 64, wn = ((threadIdx.x >> 6) & 1) * 64;
  #pragma unroll
  for (int mi = 0; mi < 4; ++mi)
    #pragma unroll
    for (int ni = 0; ni < 4; ++ni) {
      int gcol = n0 + wn + ni * 16 + (lane & 15);
      float bias = bias0[gcol];
      #pragma unroll
      for (int r = 0; r < 4; ++r) {
        int grow = m0 + wm + mi * 16 + ((lane >> 4) << 2) + r;
        float v = acc[mi][ni][r] + bias;
        if (gcol < 2560)      E0[(size_t)grow * 2560 + gcol] = f2b(fmaxf(v, 0.f));
        else if (gcol < 2586) G0L[(size_t)grow * 26 + (gcol - 2560)] = v;
      }
    }
}

// MIX0: gates softmax + expert mixing -> t1[4][B][256], sh1[B][256] (T1SH concat)
__global__ __launch_bounds__(256) void k_mix0(const u16* __restrict__ E0,
    const float* __restrict__ G0L, u16* __restrict__ T1SH)
{
  const int b = blockIdx.x;
  const int e = threadIdx.x;
  const float* gl = G0L + (size_t)b * 26;
  float g[4][4];
  #pragma unroll
  for (int t = 0; t < 4; ++t) {
    float l0 = gl[t*4+0], l1 = gl[t*4+1], l2 = gl[t*4+2], l3 = gl[t*4+3];
    float m = fmaxf(fmaxf(l0, l1), fmaxf(l2, l3));
    float e0 = expf(l0-m), e1 = expf(l1-m), e2 = expf(l2-m), e3 = expf(l3-m);
    float inv = 1.f / (e0 + e1 + e2 + e3);
    g[t][0] = e0*inv; g[t][1] = e1*inv; g[t][2] = e2*inv; g[t][3] = e3*inv;
  }
  float gs[10];
  {
    float m = gl[16];
    #pragma unroll
    for (int j = 1; j < 10; ++j) m = fmaxf(m, gl[16 + j]);
    float s = 0.f;
    #pragma unroll
    for (int j = 0; j < 10; ++j) { gs[j] = expf(gl[16 + j] - m); s += gs[j]; }
    float inv = 1.f / s;
    #pragma unroll
    for (int j = 0; j < 10; ++j) gs[j] *= inv;
  }
  const u16* row = E0 + (size_t)b * 2560;
  float sh0 = b2f(row[2048 + e]);
  float sh1 = b2f(row[2048 + 256 + e]);
  float shacc = gs[8] * sh0 + gs[9] * sh1;
  #pragma unroll
  for (int t = 0; t < 4; ++t) {
    float te0 = b2f(row[(t*2+0) * 256 + e]);
    float te1 = b2f(row[(t*2+1) * 256 + e]);
    float v = g[t][0]*te0 + g[t][1]*te1 + g[t][2]*sh0 + g[t][3]*sh1;
    T1SH[((size_t)t * B_ + b) * 256 + e] = f2b(v);
    shacc += gs[t*2+0]*te0 + gs[t*2+1]*te1;
  }
  T1SH[((size_t)4 * B_ + b) * 256 + e] = f2b(shacc);
}

// GEMM1: z<4: t1[z] x Wt1[z] (cols 0..511 experts, 512..515 gate logits);
//        z=4: sh1 x Wsh1 (cols 0..511).
__global__ __launch_bounds__(256) void k_gemm1(const u16* __restrict__ T1SH,
    const u16* __restrict__ Wt1, const float* __restrict__ bias1,
    u16* __restrict__ E1, float* __restrict__ G1L, u16* __restrict__ SH1E)
{
  __shared__ __align__(16) u16 sm[2 * 128 * 64];
  f32x4 acc[4][4];
  const int z = blockIdx.z;
  const int m0 = blockIdx.x * 128, n0 = blockIdx.y * 128;
  gemm_core(T1SH + (size_t)z * B_ * 256, Wt1 + (size_t)z * 640 * 256, 256, m0, n0, sm, sm + 8192, acc);
  const int lane = threadIdx.x & 63;
  const int wm = ((threadIdx.x >> 7) & 1) * 64, wn = ((threadIdx.x >> 6) & 1) * 64;
  const float* bias = bias1 + z * 640;
  #pragma unroll
  for (int mi = 0; mi < 4; ++mi)
    #pragma unroll
    for (int ni = 0; ni < 4; ++ni) {
      int gcol = n0 + wn + ni * 16 + (lane & 15);
      float bv = bias[gcol];
      #pragma unroll
      for (int r = 0; r < 4; ++r) {
        int grow = m0 + wm + mi * 16 + ((lane >> 4) << 2) + r;
        float v = acc[mi][ni][r] + bv;
        if (z < 4) {
          if (gcol < 512)      E1[((size_t)z * B_ + grow) * 512 + gcol] = f2b(fmaxf(v, 0.f));
          else if (gcol < 516) G1L[((size_t)z * B_ + grow) * 4 + (gcol - 512)] = v;
        } else {
          if (gcol < 512)      SH1E[(size_t)grow * 512 + gcol] = f2b(fmaxf(v, 0.f));
        }
      }
    }
}

// MIX1: gate1 softmax + mixing -> t2[4][B][256]
__global__ __launch_bounds__(256) void k_mix1(const u16* __restrict__ E1,
    const float* __restrict__ G1L, const u16* __restrict__ SH1E, u16* __restrict__ T2)
{
  const int b = blockIdx.x;
  const int e = threadIdx.x;
  float sh0 = b2f(SH1E[(size_t)b * 512 + e]);
  float sh1 = b2f(SH1E[(size_t)b * 512 + 256 + e]);
  #pragma unroll
  for (int t = 0; t < 4; ++t) {
    const float* gl = G1L + ((size_t)t * B_ + b) * 4;
    float l0 = gl[0], l1 = gl[1], l2 = gl[2], l3 = gl[3];
    float m = fmaxf(fmaxf(l0, l1), fmaxf(l2, l3));
    float e0 = expf(l0-m), e1 = expf(l1-m), e2 = expf(l2-m), e3 = expf(l3-m);
    float inv = 1.f / (e0 + e1 + e2 + e3);
    float v = (e0*inv) * b2f(E1[((size_t)t * B_ + b) * 512 + e])
            + (e1*inv) * b2f(E1[((size_t)t * B_ + b) * 512 + 256 + e])
            + (e2*inv) * sh0 + (e3*inv) * sh1;
    T2[((size_t)t * B_ + b) * 256 + e] = f2b(v);
  }
}

// TOWER: h = relu(t2[z] x Wtw[z]^T + b_tw); logits = h x w_out + b_out; softmax2; clip.
__global__ __launch_bounds__(256) void k_tower(const u16* __restrict__ T2,
    const u16* __restrict__ Wtw, const float* __restrict__ b_tw,
    const float* __restrict__ w_out, const float* __restrict__ b_out,
    float* __restrict__ out)
{
  __shared__ __align__(16) u16 sm[2 * 128 * 64];
  __shared__ float part[2][128][2];
  f32x4 acc[4][4];
  const int z = blockIdx.z;
  const int m0 = blockIdx.x * 128;
  gemm_core(T2 + (size_t)z * B_ * 256, Wtw + (size_t)z * 128 * 256, 256, m0, 0, sm, sm + 8192, acc);
  const int lane = threadIdx.x & 63;
  const int wm = ((threadIdx.x >> 7) & 1) * 64, wn = ((threadIdx.x >> 6) & 1) * 64;
  #pragma unroll
  for (int mi = 0; mi < 4; ++mi) {
    #pragma unroll
    for (int r = 0; r < 4; ++r) {
      float p0 = 0.f, p1 = 0.f;
      #pragma unroll
      for (int ni = 0; ni < 4; ++ni) {
        int col = wn + ni * 16 + (lane & 15);
        float h = fmaxf(acc[mi][ni][r] + b_tw[z * 128 + col], 0.f);
        p0 += h * w_out[(z * 128 + col) * 2 + 0];
        p1 += h * w_out[(z * 128 + col) * 2 + 1];
      }
      #pragma unroll
      for (int off = 1; off < 16; off <<= 1) {
        p0 += __shfl_xor(p0, off);
        p1 += __shfl_xor(p1, off);
      }
      if ((lane & 15) == 0) {
        int rowl = wm + mi * 16 + ((lane >> 4) << 2) + r;
        part[wn >> 6][rowl][0] = p0;
        part[wn >> 6][rowl][1] = p1;
      }
    }
  }
  __syncthreads();
  if (threadIdx.x < 128) {
    int rowl = threadIdx.x;
    float l0 = part[0][rowl][0] + part[1][rowl][0] + b_out[z * 2 + 0];
    float l1 = part[0][rowl][1] + part[1][rowl][1] + b_out[z * 2 + 1];
    float mx = fmaxf(l0, l1);
    float e0 = expf(l0 - mx), e1 = expf(l1 - mx);
    float inv = 1.f / (e0 + e1);
    float p0 = fminf(fmaxf(e0 * inv, 1e-15f), 1.0f);
    float p1 = fminf(fmaxf(e1 * inv, 1e-15f), 1.0f);
    size_t o = ((size_t)z * B_ + m0 + rowl) * 2;
    out[o] = p0; out[o + 1] = p1;
  }
}

// PREP: cast x -> bf16; build transposed bf16 weight panels + concat bias vectors.
__global__ void k_prep(const float* __restrict__ x,
    const float* __restrict__ w_task0, const float* __restrict__ b_task0,
    const float* __restrict__ w_sh0,   const float* __restrict__ b_sh0,
    const float* __restrict__ w_gate0, const float* __restrict__ b_gate0,
    const float* __restrict__ w_gsh0,  const float* __restrict__ b_gsh0,
    const float* __restrict__ w_task1, const float* __restrict__ b_task1,
    const float* __restrict__ w_sh1,   const float* __restrict__ b_sh1,
    const float* __restrict__ w_gate1, const float* __restrict__ b_gate1,
    const float* __restrict__ w_tw,
    u16* __restrict__ xb, u16* __restrict__ Wt0, float* __restrict__ bias0,
    u16* __restrict__ Wt1, float* __restrict__ bias1, u16* __restrict__ Wtw)
{
  size_t i = (size_t)blockIdx.x * 256 + threadIdx.x;
  const size_t S_XB  = (size_t)16384 * 512;   // 8388608
  const size_t S_WT0 = (size_t)2688 * 512;    // 1376256
  const size_t S_B0  = 2688;
  const size_t S_WT1 = (size_t)5 * 640 * 256; // 819200
  const size_t S_B1  = 5 * 640;               // 3200
  const size_t S_WTW = (size_t)4 * 128 * 256; // 131072

  if (i < S_XB) { xb[i] = f2b(x[i]); return; }
  i -= S_XB;
  if (i < S_WT0) {
    int c = (int)(i / 512), f = (int)(i % 512);
    float v = 0.f;
    if (c < 2048)      { int te = c >> 8, o = c & 255; v = w_task0[((size_t)te * 512 + f) * 256 + o]; }
    else if (c < 2560) { int s = (c - 2048) >> 8, o = c & 255; v = w_sh0[((size_t)s * 512 + f) * 256 + o]; }
    else if (c < 2576) { int q = c - 2560; int t = q >> 2, gg = q & 3; v = w_gate0[((size_t)t * 512 + f) * 4 + gg]; }
    else if (c < 2586) { int j = c - 2576; v = w_gsh0[(size_t)f * 10 + j]; }
    Wt0[i] = f2b(v);
    return;
  }
  i -= S_WT0;
  if (i < S_B0) {
    int c = (int)i; float v = 0.f;
    if (c < 2048)      { int te = c >> 8, o = c & 255; v = b_task0[te * 256 + o]; }
    else if (c < 2560) { int s = (c - 2048) >> 8, o = c & 255; v = b_sh0[s * 256 + o]; }
    else if (c < 2576) { v = b_gate0[c - 2560]; }
    else if (c < 2586) { v = b_gsh0[c - 2576]; }
    bias0[c] = v;
    return;
  }
  i -= S_B0;
  if (i < S_WT1) {
    int z = (int)(i / (640 * 256)); int rem = (int)(i % (640 * 256));
    int c = rem / 256, f = rem % 256;
    float v = 0.f;
    if (z < 4) {
      if (c < 512)      { int ee = c >> 8, o = c & 255; v = w_task1[(((size_t)(z * 2 + ee)) * 256 + f) * 256 + o]; }
      else if (c < 516) { int gg = c - 512; v = w_gate1[((size_t)z * 256 + f) * 4 + gg]; }
    } else {
      if (c < 512)      { int s = c >> 8, o = c & 255; v = w_sh1[((size_t)s * 256 + f) * 256 + o]; }
    }
    Wt1[i] = f2b(v);
    return;
  }
  i -= S_WT1;
  if (i < S_B1) {
    int z = (int)(i / 640); int c = (int)(i % 640);
    float v = 0.f;
    if (z < 4) {
      if (c < 512)      { int ee = c >> 8, o = c & 255; v = b_task1[(z * 2 + ee) * 256 + o]; }
      else if (c < 516) { v = b_gate1[z * 4 + (c - 512)]; }
    } else {
      if (c < 512)      { int s = c >> 8, o = c & 255; v = b_sh1[s * 256 + o]; }
    }
    bias1[(size_t)z * 640 + c] = v;
    return;
  }
  i -= S_B1;
  if (i < S_WTW) {
    int z = (int)(i / (128 * 256)); int rem = (int)(i % (128 * 256));
    int h = rem / 256, f = rem % 256;
    Wtw[i] = f2b(w_tw[((size_t)z * 256 + f) * 128 + h]);
    return;
  }
}

extern "C" void kernel_launch(void* const* d_in, const int* in_sizes, int n_in,
                              void* d_out, int out_size, void* d_ws, size_t ws_size,
                              hipStream_t stream)
{
  (void)in_sizes; (void)n_in; (void)out_size; (void)ws_size;
  const float* x       = (const float*)d_in[0];
  const float* w_task0 = (const float*)d_in[1];
  const float* b_task0 = (const float*)d_in[2];
  const float* w_sh0   = (const float*)d_in[3];
  const float* b_sh0   = (const float*)d_in[4];
  const float* w_gate0 = (const float*)d_in[5];
  const float* b_gate0 = (const float*)d_in[6];
  const float* w_gsh0  = (const float*)d_in[7];
  const float* b_gsh0  = (const float*)d_in[8];
  const float* w_task1 = (const float*)d_in[9];
  const float* b_task1 = (const float*)d_in[10];
  const float* w_sh1   = (const float*)d_in[11];
  const float* b_sh1   = (const float*)d_in[12];
  const float* w_gate1 = (const float*)d_in[13];
  const float* b_gate1 = (const float*)d_in[14];
  const float* w_tw    = (const float*)d_in[15];
  const float* b_tw    = (const float*)d_in[16];
  const float* w_out   = (const float*)d_in[17];
  const float* b_out   = (const float*)d_in[18];
  float* out = (float*)d_out;

  // ws layout (bytes, all 256-aligned). Total needed: 233,921,536 B (~223 MiB).
  char* ws = (char*)d_ws;
  u16*   XB    = (u16*)  (ws + 0);           //  16,777,216  x as bf16 [16384][512]
  u16*   WT0   = (u16*)  (ws + 16777216);    //   2,752,512  [2688][512]
  float* BIAS0 = (float*)(ws + 19529728);    //      10,752  [2688]
  u16*   WT1   = (u16*)  (ws + 19540480);    //   1,638,400  [5][640][256]
  float* BIAS1 = (float*)(ws + 21178880);    //      12,800  [5][640]
  u16*   WTW   = (u16*)  (ws + 21191680);    //     262,144  [4][128][256]
  u16*   E0    = (u16*)  (ws + 21453824);    //  83,886,080  [16384][2560]
  float* G0L   = (float*)(ws + 105339904);   //   1,703,936  [16384][26]
  u16*   T1SH  = (u16*)  (ws + 107043840);   //  41,943,040  [5][16384][256] (t1 x4, sh1)
  u16*   E1    = (u16*)  (ws + 148986880);   //  67,108,864  [4][16384][512]
  float* G1L   = (float*)(ws + 216095744);   //   1,048,576  [4][16384][4]
  u16*   SH1E  = (u16*)  (ws + 217144320);   //  16,777,216  [16384][512]
  u16*   T2    = (u16*)  (ws + 21453824);    //  33,554,432  reuses E0 (dead after k_mix0)

  k_prep<<<41879, 256, 0, stream>>>(x, w_task0, b_task0, w_sh0, b_sh0, w_gate0, b_gate0,
      w_gsh0, b_gsh0, w_task1, b_task1, w_sh1, b_sh1, w_gate1, b_gate1, w_tw,
      XB, WT0, BIAS0, WT1, BIAS1, WTW);
  k_gemm0<<<dim3(128, 21), 256, 0, stream>>>(XB, WT0, BIAS0, E0, G0L);
  k_mix0<<<16384, 256, 0, stream>>>(E0, G0L, T1SH);
  k_gemm1<<<dim3(128, 5, 5), 256, 0, stream>>>(T1SH, WT1, BIAS1, E1, G1L, SH1E);
  k_mix1<<<16384, 256, 0, stream>>>(E1, G1L, SH1E, T2);
  k_tower<<<dim3(128, 1, 4), 256, 0, stream>>>(T2, WTW, b_tw, w_out, b_out, out);
}

// Round 2
// 192.653 us; speedup vs baseline: 1.4577x; 1.4577x over previous
//
#include <hip/hip_runtime.h>

typedef unsigned short u16;
typedef __bf16 bf16x8 __attribute__((ext_vector_type(8)));
typedef float f32x4 __attribute__((ext_vector_type(4)));
typedef u16 u16x8 __attribute__((ext_vector_type(8)));

#define B_ 16384

__device__ __forceinline__ u16 f2b(float f){
  unsigned u = __builtin_bit_cast(unsigned, f);
  u = (u + 0x7FFFu + ((u >> 16) & 1u)) >> 16;   // RNE
  return (u16)u;
}
__device__ __forceinline__ float b2f(u16 v){
  return __builtin_bit_cast(float, ((unsigned)v) << 16);
}
__device__ __forceinline__ void ld8(const u16* __restrict__ p, float* f){
  u16x8 v = *(const u16x8*)p;
  #pragma unroll
  for (int j = 0; j < 8; ++j) f[j] = b2f(v[j]);
}
__device__ __forceinline__ void st8(u16* __restrict__ p, const float* f){
  u16x8 v;
  #pragma unroll
  for (int j = 0; j < 8; ++j) v[j] = f2b(f[j]);
  *(u16x8*)p = v;
}

// async global->LDS, 16B per lane; LDS dest is wave-uniform base + lane*16
__device__ __forceinline__ void gload16(const u16* g, u16* lds){
  __builtin_amdgcn_global_load_lds(
      (const __attribute__((address_space(1))) unsigned int*)g,
      (__attribute__((address_space(3))) unsigned int*)lds, 16, 0, 0);
}

// ---------------- GEMM core (global_load_lds + pre-swizzled source) ----------
// C[128,128] tile at (m0,n0) = A[m0..+128, :K) * Wt[n0..+128, :K)^T
// LDS tiles [128][64] bf16, physical slot p of row r holds logical slot p^(r&7).
// Staging: chunk c = wave*4+i covers rows c*8..c*8+7 (1 KiB each). Since
// c*8 ≡ 0 mod 8, the source swizzle is lane-only: gslot = (lane&7)^(lane>>3).
__device__ __forceinline__ void gemm_core(const u16* __restrict__ A,
                                          const u16* __restrict__ Wt,
                                          int K, int m0, int n0,
                                          u16* sA, u16* sB,
                                          f32x4 acc[4][4])
{
  const int tid  = threadIdx.x;
  const int lane = tid & 63;
  const int wave = tid >> 6;
  const int wm   = ((tid >> 7) & 1) * 64;
  const int wn   = ((tid >> 6) & 1) * 64;

  f32x4 zero = {0.f, 0.f, 0.f, 0.f};
  #pragma unroll
  for (int mi = 0; mi < 4; ++mi)
    #pragma unroll
    for (int ni = 0; ni < 4; ++ni)
      acc[mi][ni] = zero;

  const int srow  = lane >> 3;                 // 0..7 row within 8-row chunk
  const int gslot = (lane & 7) ^ srow;         // pre-swizzled source slot

  const int nsteps = K >> 6;
  for (int ks = 0; ks < nsteps; ++ks) {
    const u16* aB = A  + (size_t)(m0 + wave * 32 + srow) * K + ks * 64 + gslot * 8;
    const u16* bB = Wt + (size_t)(n0 + wave * 32 + srow) * K + ks * 64 + gslot * 8;
    u16* lA = sA + (wave * 4) * 512;
    u16* lB = sB + (wave * 4) * 512;
    #pragma unroll
    for (int i = 0; i < 4; ++i) {
      gload16(aB + (size_t)i * 8 * K, lA + i * 512);
      gload16(bB + (size_t)i * 8 * K, lB + i * 512);
    }
    __syncthreads();
    #pragma unroll
    for (int kk = 0; kk < 2; ++kk) {
      bf16x8 av[4], bv[4];
      #pragma unroll
      for (int mi = 0; mi < 4; ++mi) {
        int r = wm + mi * 16 + (lane & 15);
        int slot = kk * 4 + (lane >> 4);
        av[mi] = *(const bf16x8*)(sA + r * 64 + ((slot ^ (r & 7)) << 3));
      }
      #pragma unroll
      for (int ni = 0; ni < 4; ++ni) {
        int r = wn + ni * 16 + (lane & 15);
        int slot = kk * 4 + (lane >> 4);
        bv[ni] = *(const bf16x8*)(sB + r * 64 + ((slot ^ (r & 7)) << 3));
      }
      #pragma unroll
      for (int mi = 0; mi < 4; ++mi)
        #pragma unroll
        for (int ni = 0; ni < 4; ++ni)
          acc[mi][ni] = __builtin_amdgcn_mfma_f32_16x16x32_bf16(av[mi], bv[ni], acc[mi][ni], 0, 0, 0);
    }
    __syncthreads();
  }
}

// ---------------- stage kernels ----------------

// GEMM0: xb[16384,512] x Wt0[2688,512]^T. 1D grid 2688, XCD-swizzled.
__global__ __launch_bounds__(256) void k_gemm0(const u16* __restrict__ xb,
    const u16* __restrict__ Wt0, const float* __restrict__ bias0,
    u16* __restrict__ E0, float* __restrict__ G0L)
{
  __shared__ __align__(16) u16 sm[2 * 128 * 64];
  f32x4 acc[4][4];
  const int bid = blockIdx.x;                       // 2688 = 8 * 336
  const int swz = (bid & 7) * 336 + (bid >> 3);     // XCD gets 16 m-bands x all n
  const int m0 = (swz / 21) * 128, n0 = (swz % 21) * 128;
  gemm_core(xb, Wt0, 512, m0, n0, sm, sm + 8192, acc);
  const int lane = threadIdx.x & 63;
  const int wm = ((threadIdx.x >> 7) & 1) * 64, wn = ((threadIdx.x >> 6) & 1) * 64;
  #pragma unroll
  for (int mi = 0; mi < 4; ++mi)
    #pragma unroll
    for (int ni = 0; ni < 4; ++ni) {
      int gcol = n0 + wn + ni * 16 + (lane & 15);
      float bias = bias0[gcol];
      #pragma unroll
      for (int r = 0; r < 4; ++r) {
        int grow = m0 + wm + mi * 16 + ((lane >> 4) << 2) + r;
        float v = acc[mi][ni][r] + bias;
        if (gcol < 2560)      E0[(size_t)grow * 2560 + gcol] = f2b(fmaxf(v, 0.f));
        else if (gcol < 2586) G0L[(size_t)grow * 26 + (gcol - 2560)] = v;
      }
    }
}

// MIX0: 8 rows per block; thread (r=tid>>5, c=tid&31) handles e = c*8..+8
__global__ __launch_bounds__(256) void k_mix0(const u16* __restrict__ E0,
    const float* __restrict__ G0L, u16* __restrict__ T1SH)
{
  const int b = blockIdx.x * 8 + (threadIdx.x >> 5);
  const int e0 = (threadIdx.x & 31) * 8;
  const float* gl = G0L + (size_t)b * 26;
  float g[4][4];
  #pragma unroll
  for (int t = 0; t < 4; ++t) {
    float l0 = gl[t*4+0], l1 = gl[t*4+1], l2 = gl[t*4+2], l3 = gl[t*4+3];
    float m = fmaxf(fmaxf(l0, l1), fmaxf(l2, l3));
    float e0e = expf(l0-m), e1 = expf(l1-m), e2 = expf(l2-m), e3 = expf(l3-m);
    float inv = 1.f / (e0e + e1 + e2 + e3);
    g[t][0] = e0e*inv; g[t][1] = e1*inv; g[t][2] = e2*inv; g[t][3] = e3*inv;
  }
  float gs[10];
  {
    float m = gl[16];
    #pragma unroll
    for (int j = 1; j < 10; ++j) m = fmaxf(m, gl[16 + j]);
    float s = 0.f;
    #pragma unroll
    for (int j = 0; j < 10; ++j) { gs[j] = expf(gl[16 + j] - m); s += gs[j]; }
    float inv = 1.f / s;
    #pragma unroll
    for (int j = 0; j < 10; ++j) gs[j] *= inv;
  }
  const u16* row = E0 + (size_t)b * 2560;
  float sh0[8], sh1[8], shacc[8];
  ld8(row + 2048 + e0, sh0);
  ld8(row + 2304 + e0, sh1);
  #pragma unroll
  for (int j = 0; j < 8; ++j) shacc[j] = gs[8]*sh0[j] + gs[9]*sh1[j];
  #pragma unroll
  for (int t = 0; t < 4; ++t) {
    float te0[8], te1[8], v[8];
    ld8(row + (t*2+0)*256 + e0, te0);
    ld8(row + (t*2+1)*256 + e0, te1);
    #pragma unroll
    for (int j = 0; j < 8; ++j) {
      v[j] = g[t][0]*te0[j] + g[t][1]*te1[j] + g[t][2]*sh0[j] + g[t][3]*sh1[j];
      shacc[j] += gs[t*2+0]*te0[j] + gs[t*2+1]*te1[j];
    }
    st8(T1SH + ((size_t)t * B_ + b) * 256 + e0, v);
  }
  st8(T1SH + ((size_t)4 * B_ + b) * 256 + e0, shacc);
}

// GEMM1: z<4: t1[z] x Wt1[z] (cols 0..511 experts, 512..515 gate logits);
//        z=4: sh1 x Wsh1 (cols 0..511).
__global__ __launch_bounds__(256) void k_gemm1(const u16* __restrict__ T1SH,
    const u16* __restrict__ Wt1, const float* __restrict__ bias1,
    u16* __restrict__ E1, float* __restrict__ G1L, u16* __restrict__ SH1E)
{
  const int z = blockIdx.z;
  const int m0 = blockIdx.x * 128, n0 = blockIdx.y * 128;
  if (z == 4 && n0 >= 512) return;    // shared panel has no gate cols
  __shared__ __align__(16) u16 sm[2 * 128 * 64];
  f32x4 acc[4][4];
  gemm_core(T1SH + (size_t)z * B_ * 256, Wt1 + (size_t)z * 640 * 256, 256, m0, n0, sm, sm + 8192, acc);
  const int lane = threadIdx.x & 63;
  const int wm = ((threadIdx.x >> 7) & 1) * 64, wn = ((threadIdx.x >> 6) & 1) * 64;
  const float* bias = bias1 + z * 640;
  #pragma unroll
  for (int mi = 0; mi < 4; ++mi)
    #pragma unroll
    for (int ni = 0; ni < 4; ++ni) {
      int gcol = n0 + wn + ni * 16 + (lane & 15);
      float bv = bias[gcol];
      #pragma unroll
      for (int r = 0; r < 4; ++r) {
        int grow = m0 + wm + mi * 16 + ((lane >> 4) << 2) + r;
        float v = acc[mi][ni][r] + bv;
        if (z < 4) {
          if (gcol < 512)      E1[((size_t)z * B_ + grow) * 512 + gcol] = f2b(fmaxf(v, 0.f));
          else if (gcol < 516) G1L[((size_t)z * B_ + grow) * 4 + (gcol - 512)] = v;
        } else {
          if (gcol < 512)      SH1E[(size_t)grow * 512 + gcol] = f2b(fmaxf(v, 0.f));
        }
      }
    }
}

// MIX1: 8 rows per block, vectorized
__global__ __launch_bounds__(256) void k_mix1(const u16* __restrict__ E1,
    const float* __restrict__ G1L, const u16* __restrict__ SH1E, u16* __restrict__ T2)
{
  const int b = blockIdx.x * 8 + (threadIdx.x >> 5);
  const int e0 = (threadIdx.x & 31) * 8;
  float sh0[8], sh1[8];
  ld8(SH1E + (size_t)b * 512 + e0, sh0);
  ld8(SH1E + (size_t)b * 512 + 256 + e0, sh1);
  #pragma unroll
  for (int t = 0; t < 4; ++t) {
    const float* gl = G1L + ((size_t)t * B_ + b) * 4;
    float l0 = gl[0], l1 = gl[1], l2 = gl[2], l3 = gl[3];
    float m = fmaxf(fmaxf(l0, l1), fmaxf(l2, l3));
    float x0 = expf(l0-m), x1 = expf(l1-m), x2 = expf(l2-m), x3 = expf(l3-m);
    float inv = 1.f / (x0 + x1 + x2 + x3);
    float g0 = x0*inv, g1 = x1*inv, g2 = x2*inv, g3 = x3*inv;
    float te0[8], te1[8], v[8];
    ld8(E1 + ((size_t)t * B_ + b) * 512 + e0, te0);
    ld8(E1 + ((size_t)t * B_ + b) * 512 + 256 + e0, te1);
    #pragma unroll
    for (int j = 0; j < 8; ++j)
      v[j] = g0*te0[j] + g1*te1[j] + g2*sh0[j] + g3*sh1[j];
    st8(T2 + ((size_t)t * B_ + b) * 256 + e0, v);
  }
}

// TOWER: h = relu(t2[z] x Wtw[z]^T + b_tw); logits = h x w_out + b_out; softmax2; clip.
__global__ __launch_bounds__(256) void k_tower(const u16* __restrict__ T2,
    const u16* __restrict__ Wtw, const float* __restrict__ b_tw,
    const float* __restrict__ w_out, const float* __restrict__ b_out,
    float* __restrict__ out)
{
  __shared__ __align__(16) u16 sm[2 * 128 * 64];
  __shared__ float part[2][128][2];
  f32x4 acc[4][4];
  const int z = blockIdx.z;
  const int m0 = blockIdx.x * 128;
  gemm_core(T2 + (size_t)z * B_ * 256, Wtw + (size_t)z * 128 * 256, 256, m0, 0, sm, sm + 8192, acc);
  const int lane = threadIdx.x & 63;
  const int wm = ((threadIdx.x >> 7) & 1) * 64, wn = ((threadIdx.x >> 6) & 1) * 64;
  #pragma unroll
  for (int mi = 0; mi < 4; ++mi) {
    #pragma unroll
    for (int r = 0; r < 4; ++r) {
      float p0 = 0.f, p1 = 0.f;
      #pragma unroll
      for (int ni = 0; ni < 4; ++ni) {
        int col = wn + ni * 16 + (lane & 15);
        float h = fmaxf(acc[mi][ni][r] + b_tw[z * 128 + col], 0.f);
        p0 += h * w_out[(z * 128 + col) * 2 + 0];
        p1 += h * w_out[(z * 128 + col) * 2 + 1];
      }
      #pragma unroll
      for (int off = 1; off < 16; off <<= 1) {
        p0 += __shfl_xor(p0, off);
        p1 += __shfl_xor(p1, off);
      }
      if ((lane & 15) == 0) {
        int rowl = wm + mi * 16 + ((lane >> 4) << 2) + r;
        part[wn >> 6][rowl][0] = p0;
        part[wn >> 6][rowl][1] = p1;
      }
    }
  }
  __syncthreads();
  if (threadIdx.x < 128) {
    int rowl = threadIdx.x;
    float l0 = part[0][rowl][0] + part[1][rowl][0] + b_out[z * 2 + 0];
    float l1 = part[0][rowl][1] + part[1][rowl][1] + b_out[z * 2 + 1];
    float mx = fmaxf(l0, l1);
    float e0 = expf(l0 - mx), e1 = expf(l1 - mx);
    float inv = 1.f / (e0 + e1);
    float p0 = fminf(fmaxf(e0 * inv, 1e-15f), 1.0f);
    float p1 = fminf(fmaxf(e1 * inv, 1e-15f), 1.0f);
    size_t o = ((size_t)z * B_ + m0 + rowl) * 2;
    out[o] = p0; out[o + 1] = p1;
  }
}

// PREP: cast x -> bf16 (8 el/thread); transposed bf16 weight panels + bias vectors.
__global__ void k_prep(const float* __restrict__ x,
    const float* __restrict__ w_task0, const float* __restrict__ b_task0,
    const float* __restrict__ w_sh0,   const float* __restrict__ b_sh0,
    const float* __restrict__ w_gate0, const float* __restrict__ b_gate0,
    const float* __restrict__ w_gsh0,  const float* __restrict__ b_gsh0,
    const float* __restrict__ w_task1, const float* __restrict__ b_task1,
    const float* __restrict__ w_sh1,   const float* __restrict__ b_sh1,
    const float* __restrict__ w_gate1, const float* __restrict__ b_gate1,
    const float* __restrict__ w_tw,
    u16* __restrict__ xb, u16* __restrict__ Wt0, float* __restrict__ bias0,
    u16* __restrict__ Wt1, float* __restrict__ bias1, u16* __restrict__ Wtw)
{
  size_t i = (size_t)blockIdx.x * 256 + threadIdx.x;
  const size_t S_X8  = (size_t)16384 * 512 / 8; // 1048576 vec8 items
  const size_t S_WT0 = (size_t)2688 * 512;      // 1376256
  const size_t S_B0  = 2688;
  const size_t S_WT1 = (size_t)5 * 640 * 256;   // 819200
  const size_t S_B1  = 5 * 640;                 // 3200
  const size_t S_WTW = (size_t)4 * 128 * 256;   // 131072

  if (i < S_X8) {
    size_t o = i * 8;
    float4 a = *(const float4*)(x + o);
    float4 b = *(const float4*)(x + o + 4);
    u16x8 v;
    v[0] = f2b(a.x); v[1] = f2b(a.y); v[2] = f2b(a.z); v[3] = f2b(a.w);
    v[4] = f2b(b.x); v[5] = f2b(b.y); v[6] = f2b(b.z); v[7] = f2b(b.w);
    *(u16x8*)(xb + o) = v;
    return;
  }
  i -= S_X8;
  if (i < S_WT0) {
    int c = (int)(i / 512), f = (int)(i % 512);
    float v = 0.f;
    if (c < 2048)      { int te = c >> 8, o = c & 255; v = w_task0[((size_t)te * 512 + f) * 256 + o]; }
    else if (c < 2560) { int s = (c - 2048) >> 8, o = c & 255; v = w_sh0[((size_t)s * 512 + f) * 256 + o]; }
    else if (c < 2576) { int q = c - 2560; int t = q >> 2, gg = q & 3; v = w_gate0[((size_t)t * 512 + f) * 4 + gg]; }
    else if (c < 2586) { int j = c - 2576; v = w_gsh0[(size_t)f * 10 + j]; }
    Wt0[i] = f2b(v);
    return;
  }
  i -= S_WT0;
  if (i < S_B0) {
    int c = (int)i; float v = 0.f;
    if (c < 2048)      { int te = c >> 8, o = c & 255; v = b_task0[te * 256 + o]; }
    else if (c < 2560) { int s = (c - 2048) >> 8, o = c & 255; v = b_sh0[s * 256 + o]; }
    else if (c < 2576) { v = b_gate0[c - 2560]; }
    else if (c < 2586) { v = b_gsh0[c - 2576]; }
    bias0[c] = v;
    return;
  }
  i -= S_B0;
  if (i < S_WT1) {
    int z = (int)(i / (640 * 256)); int rem = (int)(i % (640 * 256));
    int c = rem / 256, f = rem % 256;
    float v = 0.f;
    if (z < 4) {
      if (c < 512)      { int ee = c >> 8, o = c & 255; v = w_task1[(((size_t)(z * 2 + ee)) * 256 + f) * 256 + o]; }
      else if (c < 516) { int gg = c - 512; v = w_gate1[((size_t)z * 256 + f) * 4 + gg]; }
    } else {
      if (c < 512)      { int s = c >> 8, o = c & 255; v = w_sh1[((size_t)s * 256 + f) * 256 + o]; }
    }
    Wt1[i] = f2b(v);
    return;
  }
  i -= S_WT1;
  if (i < S_B1) {
    int z = (int)(i / 640); int c = (int)(i % 640);
    float v = 0.f;
    if (z < 4) {
      if (c < 512)      { int ee = c >> 8, o = c & 255; v = b_task1[(z * 2 + ee) * 256 + o]; }
      else if (c < 516) { v = b_gate1[z * 4 + (c - 512)]; }
    } else {
      if (c < 512)      { int s = c >> 8, o = c & 255; v = b_sh1[s * 256 + o]; }
    }
    bias1[(size_t)z * 640 + c] = v;
    return;
  }
  i -= S_B1;
  if (i < S_WTW) {
    int z = (int)(i / (128 * 256)); int rem = (int)(i % (128 * 256));
    int h = rem / 256, f = rem % 256;
    Wtw[i] = f2b(w_tw[((size_t)z * 256 + f) * 128 + h]);
    return;
  }
}

extern "C" void kernel_launch(void* const* d_in, const int* in_sizes, int n_in,
                              void* d_out, int out_size, void* d_ws, size_t ws_size,
                              hipStream_t stream)
{
  (void)in_sizes; (void)n_in; (void)out_size; (void)ws_size;
  const float* x       = (const float*)d_in[0];
  const float* w_task0 = (const float*)d_in[1];
  const float* b_task0 = (const float*)d_in[2];
  const float* w_sh0   = (const float*)d_in[3];
  const float* b_sh0   = (const float*)d_in[4];
  const float* w_gate0 = (const float*)d_in[5];
  const float* b_gate0 = (const float*)d_in[6];
  const float* w_gsh0  = (const float*)d_in[7];
  const float* b_gsh0  = (const float*)d_in[8];
  const float* w_task1 = (const float*)d_in[9];
  const float* b_task1 = (const float*)d_in[10];
  const float* w_sh1   = (const float*)d_in[11];
  const float* b_sh1   = (const float*)d_in[12];
  const float* w_gate1 = (const float*)d_in[13];
  const float* b_gate1 = (const float*)d_in[14];
  const float* w_tw    = (const float*)d_in[15];
  const float* b_tw    = (const float*)d_in[16];
  const float* w_out   = (const float*)d_in[17];
  const float* b_out   = (const float*)d_in[18];
  float* out = (float*)d_out;

  char* ws = (char*)d_ws;
  u16*   XB    = (u16*)  (ws + 0);           //  16,777,216  [16384][512]
  u16*   WT0   = (u16*)  (ws + 16777216);    //   2,752,512  [2688][512]
  float* BIAS0 = (float*)(ws + 19529728);    //      10,752  [2688]
  u16*   WT1   = (u16*)  (ws + 19540480);    //   1,638,400  [5][640][256]
  float* BIAS1 = (float*)(ws + 21178880);    //      12,800  [5][640]
  u16*   WTW   = (u16*)  (ws + 21191680);    //     262,144  [4][128][256]
  u16*   E0    = (u16*)  (ws + 21453824);    //  83,886,080  [16384][2560]
  float* G0L   = (float*)(ws + 105339904);   //   1,703,936  [16384][26]
  u16*   T1SH  = (u16*)  (ws + 107043840);   //  41,943,040  [5][16384][256]
  u16*   E1    = (u16*)  (ws + 148986880);   //  67,108,864  [4][16384][512]
  float* G1L   = (float*)(ws + 216095744);   //   1,048,576  [4][16384][4]
  u16*   SH1E  = (u16*)  (ws + 217144320);   //  16,777,216  [16384][512]
  u16*   T2    = (u16*)  (ws + 21453824);    //  33,554,432  reuses E0 (dead after k_mix0)

  k_prep<<<13207, 256, 0, stream>>>(x, w_task0, b_task0, w_sh0, b_sh0, w_gate0, b_gate0,
      w_gsh0, b_gsh0, w_task1, b_task1, w_sh1, b_sh1, w_gate1, b_gate1, w_tw,
      XB, WT0, BIAS0, WT1, BIAS1, WTW);
  k_gemm0<<<2688, 256, 0, stream>>>(XB, WT0, BIAS0, E0, G0L);
  k_mix0<<<2048, 256, 0, stream>>>(E0, G0L, T1SH);
  k_gemm1<<<dim3(128, 5, 5), 256, 0, stream>>>(T1SH, WT1, BIAS1, E1, G1L, SH1E);
  k_mix1<<<2048, 256, 0, stream>>>(E1, G1L, SH1E, T2);
  k_tower<<<dim3(128, 1, 4), 256, 0, stream>>>(T2, WTW, b_tw, w_out, b_out, out);
}

// Round 3
// 181.530 us; speedup vs baseline: 1.5470x; 1.0613x over previous
//
#include <hip/hip_runtime.h>

typedef unsigned short u16;
typedef __bf16 bf16x8 __attribute__((ext_vector_type(8)));
typedef float f32x4 __attribute__((ext_vector_type(4)));
typedef u16 u16x8 __attribute__((ext_vector_type(8)));

#define B_ 16384
#define XR(r) ((((r) & 3) ^ (((r) >> 2) & 3)))

__device__ __forceinline__ u16 f2b(float f){
  unsigned u = __builtin_bit_cast(unsigned, f);
  u = (u + 0x7FFFu + ((u >> 16) & 1u)) >> 16;   // RNE
  return (u16)u;
}
__device__ __forceinline__ float b2f(u16 v){
  return __builtin_bit_cast(float, ((unsigned)v) << 16);
}
__device__ __forceinline__ void ld8(const u16* __restrict__ p, float* f){
  u16x8 v = *(const u16x8*)p;
  #pragma unroll
  for (int j = 0; j < 8; ++j) f[j] = b2f(v[j]);
}
__device__ __forceinline__ void st8(u16* __restrict__ p, const float* f){
  u16x8 v;
  #pragma unroll
  for (int j = 0; j < 8; ++j) v[j] = f2b(f[j]);
  *(u16x8*)p = v;
}

__device__ __forceinline__ void gload16(const u16* g, u16* lds){
  __builtin_amdgcn_global_load_lds(
      (const __attribute__((address_space(1))) unsigned int*)g,
      (__attribute__((address_space(3))) unsigned int*)lds, 16, 0, 0);
}

// ---------------- GEMM core v2: ring-3 deep pipeline ----------------
// BM=256, BN=128, BK=32. 512 threads = 8 waves (4M x 2N), per-wave 64x64
// (acc[4][4] of 16x16x32 frags). LDS: 3 slots x (A[256][32] + B[128][32]) bf16
// = 73728 B. 16B slots XOR-swizzled: phys = s ^ (r&3) ^ ((r>>2)&3), applied on
// the pre-swizzled global source (LDS dest stays linear for global_load_lds).
// Schedule per K-step: STAGE(j+2) -> ds_read(j) -> MFMA -> vmcnt(3) -> barrier.
// vmcnt(3) leaves only stage(j+2)'s 3 loads outstanding => tile j+1 landed.
__device__ __forceinline__ void gemm_core2(const u16* __restrict__ A,
                                           const u16* __restrict__ Wt,
                                           int K, int m0, int n0, int nt,
                                           u16* sm, f32x4 acc[4][4])
{
  const int tid  = threadIdx.x;
  const int lane = tid & 63;
  const int wm   = ((tid >> 7) & 3) * 64;
  const int wn   = ((tid >> 6) & 1) * 64;

  f32x4 zero = {0.f, 0.f, 0.f, 0.f};
  #pragma unroll
  for (int mi = 0; mi < 4; ++mi)
    #pragma unroll
    for (int ni = 0; ni < 4; ++ni) acc[mi][ni] = zero;

  // staging: fixed per-thread source coords (pre-swizzled)
  const int rA0 = tid >> 2, rA1 = 128 + (tid >> 2), rB = tid >> 2;
  const u16* gA0 = A  + (size_t)(m0 + rA0) * K + (((tid & 3) ^ XR(rA0)) * 8);
  const u16* gA1 = A  + (size_t)(m0 + rA1) * K + (((tid & 3) ^ XR(rA1)) * 8);
  const u16* gB  = Wt + (size_t)(n0 + rB ) * K + (((tid & 3) ^ XR(rB )) * 8);
  const int wbase = (tid >> 6) * 512;   // wave-uniform LDS base (u16 units)

  // ds-read offsets (u16 units), fixed per thread across the ring
  int aoff[4], boff[4];
  #pragma unroll
  for (int m = 0; m < 4; ++m) {
    int r = wm + m * 16 + (lane & 15);
    aoff[m] = r * 32 + (((lane >> 4) ^ XR(r)) * 8);
  }
  #pragma unroll
  for (int n = 0; n < 4; ++n) {
    int r = wn + n * 16 + (lane & 15);
    boff[n] = r * 32 + (((lane >> 4) ^ XR(r)) * 8);
  }

  // prologue: stage tiles 0,1 into slots 0,1 (6 loads/thread)
  #pragma unroll
  for (int j = 0; j < 2; ++j) {
    u16* sl = sm + j * 12288;
    gload16(gA0 + j * 32, sl + wbase);
    gload16(gA1 + j * 32, sl + 4096 + wbase);
    gload16(gB  + j * 32, sl + 8192 + wbase);
  }
  asm volatile("s_waitcnt vmcnt(3)" ::: "memory");   // tile 0 landed
  __builtin_amdgcn_s_barrier();

  int cs = 0;
  for (int j = 0; j < nt; ++j) {
    if (j + 2 < nt) {                      // stage j+2 into slot of tile j-1
      int ns = cs + 2; ns = (ns >= 3) ? ns - 3 : ns;
      u16* sl = sm + ns * 12288;
      gload16(gA0 + (size_t)(j + 2) * 32, sl + wbase);
      gload16(gA1 + (size_t)(j + 2) * 32, sl + 4096 + wbase);
      gload16(gB  + (size_t)(j + 2) * 32, sl + 8192 + wbase);
    }
    const u16* sa = sm + cs * 12288;
    const u16* sb = sa + 8192;
    bf16x8 av[4], bv[4];
    #pragma unroll
    for (int m = 0; m < 4; ++m) av[m] = *(const bf16x8*)(sa + aoff[m]);
    #pragma unroll
    for (int n = 0; n < 4; ++n) bv[n] = *(const bf16x8*)(sb + boff[n]);
    #pragma unroll
    for (int m = 0; m < 4; ++m)
      #pragma unroll
      for (int n = 0; n < 4; ++n)
        acc[m][n] = __builtin_amdgcn_mfma_f32_16x16x32_bf16(av[m], bv[n], acc[m][n], 0, 0, 0);
    if (j + 2 < nt)      asm volatile("s_waitcnt vmcnt(3)" ::: "memory");
    else if (j + 1 < nt) asm volatile("s_waitcnt vmcnt(0)" ::: "memory");
    __builtin_amdgcn_s_barrier();
    cs = (cs == 2) ? 0 : cs + 1;
  }
}

// ---------------- stage kernels ----------------

// GEMM0: xb[16384,512] x Wt0[2688,512]^T. grid 1344 = 64 m x 21 n, XCD-swizzled.
__global__ __launch_bounds__(512) void k_gemm0(const u16* __restrict__ xb,
    const u16* __restrict__ Wt0, const float* __restrict__ bias0,
    u16* __restrict__ E0, float* __restrict__ G0L)
{
  __shared__ __align__(16) u16 sm[36864];
  f32x4 acc[4][4];
  const int bid = blockIdx.x;                       // 1344 = 8 * 168
  const int swz = (bid & 7) * 168 + (bid >> 3);
  const int m0 = (swz / 21) * 256, n0 = (swz % 21) * 128;
  gemm_core2(xb, Wt0, 512, m0, n0, 16, sm, acc);
  const int lane = threadIdx.x & 63;
  const int wm = ((threadIdx.x >> 7) & 3) * 64, wn = ((threadIdx.x >> 6) & 1) * 64;
  #pragma unroll
  for (int mi = 0; mi < 4; ++mi)
    #pragma unroll
    for (int ni = 0; ni < 4; ++ni) {
      int gcol = n0 + wn + ni * 16 + (lane & 15);
      float bias = bias0[gcol];
      #pragma unroll
      for (int r = 0; r < 4; ++r) {
        int grow = m0 + wm + mi * 16 + ((lane >> 4) << 2) + r;
        float v = acc[mi][ni][r] + bias;
        if (gcol < 2560)      E0[(size_t)grow * 2560 + gcol] = f2b(fmaxf(v, 0.f));
        else if (gcol < 2586) G0L[(size_t)grow * 26 + (gcol - 2560)] = v;
      }
    }
}

// MIX0: 8 rows per block; thread (r=tid>>5, c=tid&31) handles e = c*8..+8
__global__ __launch_bounds__(256) void k_mix0(const u16* __restrict__ E0,
    const float* __restrict__ G0L, u16* __restrict__ T1SH)
{
  const int b = blockIdx.x * 8 + (threadIdx.x >> 5);
  const int e0 = (threadIdx.x & 31) * 8;
  const float* gl = G0L + (size_t)b * 26;
  float g[4][4];
  #pragma unroll
  for (int t = 0; t < 4; ++t) {
    float l0 = gl[t*4+0], l1 = gl[t*4+1], l2 = gl[t*4+2], l3 = gl[t*4+3];
    float m = fmaxf(fmaxf(l0, l1), fmaxf(l2, l3));
    float e0e = expf(l0-m), e1 = expf(l1-m), e2 = expf(l2-m), e3 = expf(l3-m);
    float inv = 1.f / (e0e + e1 + e2 + e3);
    g[t][0] = e0e*inv; g[t][1] = e1*inv; g[t][2] = e2*inv; g[t][3] = e3*inv;
  }
  float gs[10];
  {
    float m = gl[16];
    #pragma unroll
    for (int j = 1; j < 10; ++j) m = fmaxf(m, gl[16 + j]);
    float s = 0.f;
    #pragma unroll
    for (int j = 0; j < 10; ++j) { gs[j] = expf(gl[16 + j] - m); s += gs[j]; }
    float inv = 1.f / s;
    #pragma unroll
    for (int j = 0; j < 10; ++j) gs[j] *= inv;
  }
  const u16* row = E0 + (size_t)b * 2560;
  float sh0[8], sh1[8], shacc[8];
  ld8(row + 2048 + e0, sh0);
  ld8(row + 2304 + e0, sh1);
  #pragma unroll
  for (int j = 0; j < 8; ++j) shacc[j] = gs[8]*sh0[j] + gs[9]*sh1[j];
  #pragma unroll
  for (int t = 0; t < 4; ++t) {
    float te0[8], te1[8], v[8];
    ld8(row + (t*2+0)*256 + e0, te0);
    ld8(row + (t*2+1)*256 + e0, te1);
    #pragma unroll
    for (int j = 0; j < 8; ++j) {
      v[j] = g[t][0]*te0[j] + g[t][1]*te1[j] + g[t][2]*sh0[j] + g[t][3]*sh1[j];
      shacc[j] += gs[t*2+0]*te0[j] + gs[t*2+1]*te1[j];
    }
    st8(T1SH + ((size_t)t * B_ + b) * 256 + e0, v);
  }
  st8(T1SH + ((size_t)4 * B_ + b) * 256 + e0, shacc);
}

// GEMM1: z<4: t1[z] x Wt1[z] (cols 0..511 experts, 512..515 gate logits);
//        z=4: sh1 x Wsh1 (cols 0..511).
__global__ __launch_bounds__(512) void k_gemm1(const u16* __restrict__ T1SH,
    const u16* __restrict__ Wt1, const float* __restrict__ bias1,
    u16* __restrict__ E1, float* __restrict__ G1L, u16* __restrict__ SH1E)
{
  const int z = blockIdx.z;
  const int m0 = blockIdx.x * 256, n0 = blockIdx.y * 128;
  if (z == 4 && n0 >= 512) return;    // shared panel has no gate cols
  __shared__ __align__(16) u16 sm[36864];
  f32x4 acc[4][4];
  gemm_core2(T1SH + (size_t)z * B_ * 256, Wt1 + (size_t)z * 640 * 256, 256, m0, n0, 8, sm, acc);
  const int lane = threadIdx.x & 63;
  const int wm = ((threadIdx.x >> 7) & 3) * 64, wn = ((threadIdx.x >> 6) & 1) * 64;
  const float* bias = bias1 + z * 640;
  #pragma unroll
  for (int mi = 0; mi < 4; ++mi)
    #pragma unroll
    for (int ni = 0; ni < 4; ++ni) {
      int gcol = n0 + wn + ni * 16 + (lane & 15);
      float bv = bias[gcol];
      #pragma unroll
      for (int r = 0; r < 4; ++r) {
        int grow = m0 + wm + mi * 16 + ((lane >> 4) << 2) + r;
        float v = acc[mi][ni][r] + bv;
        if (z < 4) {
          if (gcol < 512)      E1[((size_t)z * B_ + grow) * 512 + gcol] = f2b(fmaxf(v, 0.f));
          else if (gcol < 516) G1L[((size_t)z * B_ + grow) * 4 + (gcol - 512)] = v;
        } else {
          if (gcol < 512)      SH1E[(size_t)grow * 512 + gcol] = f2b(fmaxf(v, 0.f));
        }
      }
    }
}

// MIX1: 8 rows per block, vectorized
__global__ __launch_bounds__(256) void k_mix1(const u16* __restrict__ E1,
    const float* __restrict__ G1L, const u16* __restrict__ SH1E, u16* __restrict__ T2)
{
  const int b = blockIdx.x * 8 + (threadIdx.x >> 5);
  const int e0 = (threadIdx.x & 31) * 8;
  float sh0[8], sh1[8];
  ld8(SH1E + (size_t)b * 512 + e0, sh0);
  ld8(SH1E + (size_t)b * 512 + 256 + e0, sh1);
  #pragma unroll
  for (int t = 0; t < 4; ++t) {
    const float* gl = G1L + ((size_t)t * B_ + b) * 4;
    float l0 = gl[0], l1 = gl[1], l2 = gl[2], l3 = gl[3];
    float m = fmaxf(fmaxf(l0, l1), fmaxf(l2, l3));
    float x0 = expf(l0-m), x1 = expf(l1-m), x2 = expf(l2-m), x3 = expf(l3-m);
    float inv = 1.f / (x0 + x1 + x2 + x3);
    float g0 = x0*inv, g1 = x1*inv, g2 = x2*inv, g3 = x3*inv;
    float te0[8], te1[8], v[8];
    ld8(E1 + ((size_t)t * B_ + b) * 512 + e0, te0);
    ld8(E1 + ((size_t)t * B_ + b) * 512 + 256 + e0, te1);
    #pragma unroll
    for (int j = 0; j < 8; ++j)
      v[j] = g0*te0[j] + g1*te1[j] + g2*sh0[j] + g3*sh1[j];
    st8(T2 + ((size_t)t * B_ + b) * 256 + e0, v);
  }
}

// TOWER: h = relu(t2[z] x Wtw[z]^T + b_tw); logits = h x w_out + b_out; softmax2; clip.
__global__ __launch_bounds__(512) void k_tower(const u16* __restrict__ T2,
    const u16* __restrict__ Wtw, const float* __restrict__ b_tw,
    const float* __restrict__ w_out, const float* __restrict__ b_out,
    float* __restrict__ out)
{
  __shared__ __align__(16) u16 sm[36864];
  __shared__ float part[2][256][2];
  f32x4 acc[4][4];
  const int z = blockIdx.z;
  const int m0 = blockIdx.x * 256;
  gemm_core2(T2 + (size_t)z * B_ * 256, Wtw + (size_t)z * 128 * 256, 256, m0, 0, 8, sm, acc);
  const int lane = threadIdx.x & 63;
  const int wm = ((threadIdx.x >> 7) & 3) * 64, wn = ((threadIdx.x >> 6) & 1) * 64;
  #pragma unroll
  for (int mi = 0; mi < 4; ++mi) {
    #pragma unroll
    for (int r = 0; r < 4; ++r) {
      float p0 = 0.f, p1 = 0.f;
      #pragma unroll
      for (int ni = 0; ni < 4; ++ni) {
        int col = wn + ni * 16 + (lane & 15);
        float h = fmaxf(acc[mi][ni][r] + b_tw[z * 128 + col], 0.f);
        p0 += h * w_out[(z * 128 + col) * 2 + 0];
        p1 += h * w_out[(z * 128 + col) * 2 + 1];
      }
      #pragma unroll
      for (int off = 1; off < 16; off <<= 1) {
        p0 += __shfl_xor(p0, off);
        p1 += __shfl_xor(p1, off);
      }
      if ((lane & 15) == 0) {
        int rowl = wm + mi * 16 + ((lane >> 4) << 2) + r;
        part[(threadIdx.x >> 6) & 1][rowl][0] = p0;
        part[(threadIdx.x >> 6) & 1][rowl][1] = p1;
      }
    }
  }
  __syncthreads();
  if (threadIdx.x < 256) {
    int rowl = threadIdx.x;
    float l0 = part[0][rowl][0] + part[1][rowl][0] + b_out[z * 2 + 0];
    float l1 = part[0][rowl][1] + part[1][rowl][1] + b_out[z * 2 + 1];
    float mx = fmaxf(l0, l1);
    float e0 = expf(l0 - mx), e1 = expf(l1 - mx);
    float inv = 1.f / (e0 + e1);
    float p0 = fminf(fmaxf(e0 * inv, 1e-15f), 1.0f);
    float p1 = fminf(fmaxf(e1 * inv, 1e-15f), 1.0f);
    size_t o = ((size_t)z * B_ + m0 + rowl) * 2;
    out[o] = p0; out[o + 1] = p1;
  }
}

// PREP: cast x -> bf16 (8 el/thread); transposed bf16 weight panels + bias vectors.
__global__ void k_prep(const float* __restrict__ x,
    const float* __restrict__ w_task0, const float* __restrict__ b_task0,
    const float* __restrict__ w_sh0,   const float* __restrict__ b_sh0,
    const float* __restrict__ w_gate0, const float* __restrict__ b_gate0,
    const float* __restrict__ w_gsh0,  const float* __restrict__ b_gsh0,
    const float* __restrict__ w_task1, const float* __restrict__ b_task1,
    const float* __restrict__ w_sh1,   const float* __restrict__ b_sh1,
    const float* __restrict__ w_gate1, const float* __restrict__ b_gate1,
    const float* __restrict__ w_tw,
    u16* __restrict__ xb, u16* __restrict__ Wt0, float* __restrict__ bias0,
    u16* __restrict__ Wt1, float* __restrict__ bias1, u16* __restrict__ Wtw)
{
  size_t i = (size_t)blockIdx.x * 256 + threadIdx.x;
  const size_t S_X8  = (size_t)16384 * 512 / 8; // 1048576 vec8 items
  const size_t S_WT0 = (size_t)2688 * 512;      // 1376256
  const size_t S_B0  = 2688;
  const size_t S_WT1 = (size_t)5 * 640 * 256;   // 819200
  const size_t S_B1  = 5 * 640;                 // 3200
  const size_t S_WTW = (size_t)4 * 128 * 256;   // 131072

  if (i < S_X8) {
    size_t o = i * 8;
    float4 a = *(const float4*)(x + o);
    float4 b = *(const float4*)(x + o + 4);
    u16x8 v;
    v[0] = f2b(a.x); v[1] = f2b(a.y); v[2] = f2b(a.z); v[3] = f2b(a.w);
    v[4] = f2b(b.x); v[5] = f2b(b.y); v[6] = f2b(b.z); v[7] = f2b(b.w);
    *(u16x8*)(xb + o) = v;
    return;
  }
  i -= S_X8;
  if (i < S_WT0) {
    int c = (int)(i / 512), f = (int)(i % 512);
    float v = 0.f;
    if (c < 2048)      { int te = c >> 8, o = c & 255; v = w_task0[((size_t)te * 512 + f) * 256 + o]; }
    else if (c < 2560) { int s = (c - 2048) >> 8, o = c & 255; v = w_sh0[((size_t)s * 512 + f) * 256 + o]; }
    else if (c < 2576) { int q = c - 2560; int t = q >> 2, gg = q & 3; v = w_gate0[((size_t)t * 512 + f) * 4 + gg]; }
    else if (c < 2586) { int j = c - 2576; v = w_gsh0[(size_t)f * 10 + j]; }
    Wt0[i] = f2b(v);
    return;
  }
  i -= S_WT0;
  if (i < S_B0) {
    int c = (int)i; float v = 0.f;
    if (c < 2048)      { int te = c >> 8, o = c & 255; v = b_task0[te * 256 + o]; }
    else if (c < 2560) { int s = (c - 2048) >> 8, o = c & 255; v = b_sh0[s * 256 + o]; }
    else if (c < 2576) { v = b_gate0[c - 2560]; }
    else if (c < 2586) { v = b_gsh0[c - 2576]; }
    bias0[c] = v;
    return;
  }
  i -= S_B0;
  if (i < S_WT1) {
    int z = (int)(i / (640 * 256)); int rem = (int)(i % (640 * 256));
    int c = rem / 256, f = rem % 256;
    float v = 0.f;
    if (z < 4) {
      if (c < 512)      { int ee = c >> 8, o = c & 255; v = w_task1[(((size_t)(z * 2 + ee)) * 256 + f) * 256 + o]; }
      else if (c < 516) { int gg = c - 512; v = w_gate1[((size_t)z * 256 + f) * 4 + gg]; }
    } else {
      if (c < 512)      { int s = c >> 8, o = c & 255; v = w_sh1[((size_t)s * 256 + f) * 256 + o]; }
    }
    Wt1[i] = f2b(v);
    return;
  }
  i -= S_WT1;
  if (i < S_B1) {
    int z = (int)(i / 640); int c = (int)(i % 640);
    float v = 0.f;
    if (z < 4) {
      if (c < 512)      { int ee = c >> 8, o = c & 255; v = b_task1[(z * 2 + ee) * 256 + o]; }
      else if (c < 516) { v = b_gate1[z * 4 + (c - 512)]; }
    } else {
      if (c < 512)      { int s = c >> 8, o = c & 255; v = b_sh1[s * 256 + o]; }
    }
    bias1[(size_t)z * 640 + c] = v;
    return;
  }
  i -= S_B1;
  if (i < S_WTW) {
    int z = (int)(i / (128 * 256)); int rem = (int)(i % (128 * 256));
    int h = rem / 256, f = rem % 256;
    Wtw[i] = f2b(w_tw[((size_t)z * 256 + f) * 128 + h]);
    return;
  }
}

extern "C" void kernel_launch(void* const* d_in, const int* in_sizes, int n_in,
                              void* d_out, int out_size, void* d_ws, size_t ws_size,
                              hipStream_t stream)
{
  (void)in_sizes; (void)n_in; (void)out_size; (void)ws_size;
  const float* x       = (const float*)d_in[0];
  const float* w_task0 = (const float*)d_in[1];
  const float* b_task0 = (const float*)d_in[2];
  const float* w_sh0   = (const float*)d_in[3];
  const float* b_sh0   = (const float*)d_in[4];
  const float* w_gate0 = (const float*)d_in[5];
  const float* b_gate0 = (const float*)d_in[6];
  const float* w_gsh0  = (const float*)d_in[7];
  const float* b_gsh0  = (const float*)d_in[8];
  const float* w_task1 = (const float*)d_in[9];
  const float* b_task1 = (const float*)d_in[10];
  const float* w_sh1   = (const float*)d_in[11];
  const float* b_sh1   = (const float*)d_in[12];
  const float* w_gate1 = (const float*)d_in[13];
  const float* b_gate1 = (const float*)d_in[14];
  const float* w_tw    = (const float*)d_in[15];
  const float* b_tw    = (const float*)d_in[16];
  const float* w_out   = (const float*)d_in[17];
  const float* b_out   = (const float*)d_in[18];
  float* out = (float*)d_out;

  char* ws = (char*)d_ws;
  u16*   XB    = (u16*)  (ws + 0);           //  16,777,216  [16384][512]
  u16*   WT0   = (u16*)  (ws + 16777216);    //   2,752,512  [2688][512]
  float* BIAS0 = (float*)(ws + 19529728);    //      10,752  [2688]
  u16*   WT1   = (u16*)  (ws + 19540480);    //   1,638,400  [5][640][256]
  float* BIAS1 = (float*)(ws + 21178880);    //      12,800  [5][640]
  u16*   WTW   = (u16*)  (ws + 21191680);    //     262,144  [4][128][256]
  u16*   E0    = (u16*)  (ws + 21453824);    //  83,886,080  [16384][2560]
  float* G0L   = (float*)(ws + 105339904);   //   1,703,936  [16384][26]
  u16*   T1SH  = (u16*)  (ws + 107043840);   //  41,943,040  [5][16384][256]
  u16*   E1    = (u16*)  (ws + 148986880);   //  67,108,864  [4][16384][512]
  float* G1L   = (float*)(ws + 216095744);   //   1,048,576  [4][16384][4]
  u16*   SH1E  = (u16*)  (ws + 217144320);   //  16,777,216  [16384][512]
  u16*   T2    = (u16*)  (ws + 21453824);    //  33,554,432  reuses E0 (dead after k_mix0)

  k_prep<<<13207, 256, 0, stream>>>(x, w_task0, b_task0, w_sh0, b_sh0, w_gate0, b_gate0,
      w_gsh0, b_gsh0, w_task1, b_task1, w_sh1, b_sh1, w_gate1, b_gate1, w_tw,
      XB, WT0, BIAS0, WT1, BIAS1, WTW);
  k_gemm0<<<1344, 512, 0, stream>>>(XB, WT0, BIAS0, E0, G0L);
  k_mix0<<<2048, 256, 0, stream>>>(E0, G0L, T1SH);
  k_gemm1<<<dim3(64, 5, 5), 512, 0, stream>>>(T1SH, WT1, BIAS1, E1, G1L, SH1E);
  k_mix1<<<2048, 256, 0, stream>>>(E1, G1L, SH1E, T2);
  k_tower<<<dim3(64, 1, 4), 512, 0, stream>>>(T2, WTW, b_tw, w_out, b_out, out);
}